// Round 15
// baseline (686.745 us; speedup 1.0000x reference)
//
#include <hip/hip_runtime.h>
#include <cstddef>

#define NB 32
#define NS 64
#define NH 768
#define NSEG_ (NB*NS)      // 2048
#define NIN 816
#define G4 3072
#define HOR_ 24
#define FBLK 192           // merged blocks: each owns 4 j of L0 + 4 j of L1
#define LTHR 512           // 8 waves/block

// MFMA fragment types (short-based bf16, compile-verified on gfx950)
typedef __attribute__((ext_vector_type(8))) short bf16x8;
typedef __attribute__((ext_vector_type(4))) float f32x4;
typedef __attribute__((ext_vector_type(8))) unsigned short u16x8;

// lstm dynamic-LDS: ONE packed-u32 h plane [32][772] + partial-C [8][16][33]
#define HPW 772            // plane row stride in u32 (768 + 4 pad, 16B-aligned)
#define SMEM_BYTES ((32*HPW + 8*528) * 4)   // 98816 + 16896 = 115712

// workspace offsets (floats / u32s)
#define OFF_X      0
#define SZ_X       (NSEG_*NIN)
#define OFF_MEAN   (OFF_X + SZ_X)
#define SZ_MEAN    (NSEG_*NH)
#define OFF_TMP    (OFF_MEAN + SZ_MEAN)
#define OFF_H0PK   (OFF_TMP + SZ_MEAN)      // [2048][768] packed bf16 hi|lo
#define OFF_H1PK   (OFF_H0PK + SZ_MEAN)
#define OFF_XG     (OFF_H1PK + SZ_MEAN)
#define SZ_XG      (NSEG_*G4)
#define OFF_HZERO  (OFF_XG + SZ_XG)
#define SZ_HZERO   (NB*NH)
#define OFF_FLG    (OFF_HZERO + SZ_HZERO)   // 192 flag slots, 16B apart

// agent-scope write-through store (coherence point; proven r6)
__device__ __forceinline__ void coh_store_u32(unsigned* p, unsigned v) {
  __hip_atomic_store(p, v, __ATOMIC_RELAXED, __HIP_MEMORY_SCOPE_AGENT);
}

// split a float into bf16 hi + bf16 residual
__device__ __forceinline__ void split_bf16(float v, unsigned short& hi,
                                           unsigned short& lo) {
  const unsigned u = __float_as_uint(v);
  hi = (unsigned short)(u >> 16);
  const float rem = v - __uint_as_float(u & 0xffff0000u);
  lo = (unsigned short)(__float_as_uint(rem) >> 16);
}

// async DMA: copy [32][768] u32 row-major global -> LDS plane [32][HPW].
// Wave w copies rows w*4..w*4+3 (3x 1024B chunks per row); per chunk the
// 64 lanes each move 16B (global src per-lane, LDS dest = uniform base +
// lane*16 -- the global_load_lds contract).  No VGPR round-trip, no VALU.
__device__ __forceinline__ void async_stage(const unsigned* __restrict__ src,
                                            unsigned* plane, int wid, int lane) {
  #pragma unroll
  for (int r4 = 0; r4 < 4; ++r4) {
    const int row = wid * 4 + r4;
    #pragma unroll
    for (int part = 0; part < 3; ++part) {
      const unsigned* g = src + (size_t)row * NH + part * 256 + lane * 4;
      unsigned* l = plane + row * HPW + part * 256;
      __builtin_amdgcn_global_load_lds(
          (const __attribute__((address_space(1))) void*)g,
          (__attribute__((address_space(3))) void*)l, 16, 0, 0);
    }
  }
}

// read a bf16x8 hi/lo fragment pair from the packed plane (2 shifts/elem;
// values bit-identical to the former hi/lo-plane layout)
__device__ __forceinline__ void read_frag(const unsigned* __restrict__ plane,
                                          int idx, bf16x8& hi, bf16x8& lo) {
  const uint4 w0 = *(const uint4*)(plane + idx);
  const uint4 w1 = *(const uint4*)(plane + idx + 4);
  const unsigned ww[8] = {w0.x, w0.y, w0.z, w0.w, w1.x, w1.y, w1.z, w1.w};
  #pragma unroll
  for (int i = 0; i < 8; ++i) {
    hi[i] = (short)(ww[i] >> 16);
    lo[i] = (short)(ww[i] & 0xffffu);
  }
}

// ---------------------------------------------------------------------------
// Segment mean: encs [65536,768] -> mean [2048,768]
// ---------------------------------------------------------------------------
__global__ __launch_bounds__(192) void seg_mean_kernel(
    const float* __restrict__ encs, float* __restrict__ mean) {
  const int s = blockIdx.x;
  const int t = threadIdx.x;
  const float4* base = (const float4*)(encs + (size_t)s * 32 * NH);
  float4 a = {0.f, 0.f, 0.f, 0.f};
  #pragma unroll 4
  for (int r = 0; r < 32; ++r) {
    float4 v = base[(size_t)r * (NH / 4) + t];
    a.x += v.x; a.y += v.y; a.z += v.z; a.w += v.w;
  }
  const float inv = 1.f / 32.f;
  float4 o = {a.x * inv, a.y * inv, a.z * inv, a.w * inv};
  ((float4*)mean)[(size_t)s * (NH / 4) + t] = o;
}

// ---------------------------------------------------------------------------
// Split-bf16 MFMA GEMM: C[M,N] = A[M,K] @ W[N,K]^T + bias1[n] + bias2[n]
// (round-10 proven: ~fp32 accuracy via hi.hi + hi.lo + lo.hi)
// ---------------------------------------------------------------------------
__global__ __launch_bounds__(256) void gemm_mfma_nt(
    const float* __restrict__ A, const float* __restrict__ W,
    const float* __restrict__ bias1, const float* __restrict__ bias2,
    float* __restrict__ C, int M, int N, int K) {
  __shared__ unsigned short Ahi[64 * 40];
  __shared__ unsigned short Alo[64 * 40];
  __shared__ unsigned short Whi[64 * 40];
  __shared__ unsigned short Wlo[64 * 40];
  const int tid = threadIdx.x;
  const int bm = blockIdx.y, bn = blockIdx.x;
  const int lane = tid & 63;
  const int wid  = tid >> 6;
  const int lm = lane & 15;
  const int lk = lane >> 4;
  const int srow = tid >> 2;
  const int skc  = (tid & 3) * 8;

  const float* Ap = A + (size_t)(bm * 64 + srow) * K;
  const float* Wp = W + (size_t)(bn * 64 + srow) * K;

  f32x4 acc[4];
  #pragma unroll
  for (int nf = 0; nf < 4; ++nf) acc[nf] = (f32x4){0.f, 0.f, 0.f, 0.f};

  for (int k0 = 0; k0 < K; k0 += 32) {
    float va[8], vw[8];
    if (k0 + skc + 8 <= K) {
      float4 a0 = *(const float4*)(Ap + k0 + skc);
      float4 a1 = *(const float4*)(Ap + k0 + skc + 4);
      float4 w0 = *(const float4*)(Wp + k0 + skc);
      float4 w1 = *(const float4*)(Wp + k0 + skc + 4);
      va[0]=a0.x; va[1]=a0.y; va[2]=a0.z; va[3]=a0.w;
      va[4]=a1.x; va[5]=a1.y; va[6]=a1.z; va[7]=a1.w;
      vw[0]=w0.x; vw[1]=w0.y; vw[2]=w0.z; vw[3]=w0.w;
      vw[4]=w1.x; vw[5]=w1.y; vw[6]=w1.z; vw[7]=w1.w;
    } else {
      #pragma unroll
      for (int i = 0; i < 8; ++i) { va[i] = 0.f; vw[i] = 0.f; }
    }
    u16x8 AH, AL, WH, WL;
    #pragma unroll
    for (int i = 0; i < 8; ++i) {
      unsigned short h, l;
      split_bf16(va[i], h, l); AH[i] = h; AL[i] = l;
      split_bf16(vw[i], h, l); WH[i] = h; WL[i] = l;
    }
    __syncthreads();
    *(u16x8*)(&Ahi[srow * 40 + skc]) = AH;
    *(u16x8*)(&Alo[srow * 40 + skc]) = AL;
    *(u16x8*)(&Whi[srow * 40 + skc]) = WH;
    *(u16x8*)(&Wlo[srow * 40 + skc]) = WL;
    __syncthreads();
    bf16x8 ah = *(bf16x8*)(&Ahi[(wid * 16 + lm) * 40 + lk * 8]);
    bf16x8 al = *(bf16x8*)(&Alo[(wid * 16 + lm) * 40 + lk * 8]);
    #pragma unroll
    for (int nf = 0; nf < 4; ++nf) {
      bf16x8 bh = *(bf16x8*)(&Whi[(nf * 16 + lm) * 40 + lk * 8]);
      bf16x8 bl = *(bf16x8*)(&Wlo[(nf * 16 + lm) * 40 + lk * 8]);
      acc[nf] = __builtin_amdgcn_mfma_f32_16x16x32_bf16(ah, bh, acc[nf], 0, 0, 0);
      acc[nf] = __builtin_amdgcn_mfma_f32_16x16x32_bf16(ah, bl, acc[nf], 0, 0, 0);
      acc[nf] = __builtin_amdgcn_mfma_f32_16x16x32_bf16(al, bh, acc[nf], 0, 0, 0);
    }
  }
  #pragma unroll
  for (int nf = 0; nf < 4; ++nf) {
    const int gn = bn * 64 + nf * 16 + lm;
    float bb = 0.f;
    if (bias1) bb += bias1[gn];
    if (bias2) bb += bias2[gn];
    #pragma unroll
    for (int r4 = 0; r4 < 4; ++r4) {
      const int gm = bm * 64 + wid * 16 + lk * 4 + r4;
      C[(size_t)gm * N + gn] = acc[nf][r4] + bb;
    }
  }
}

// ---------------------------------------------------------------------------
// x[s*32+b][0:816] = concat(z[b,s], cond[b,s], encoded[b*64+s])
// ---------------------------------------------------------------------------
__global__ __launch_bounds__(256) void build_x_kernel(
    const float* __restrict__ z, const float* __restrict__ cond,
    const float* __restrict__ enc, float* __restrict__ x) {
  const int idx = blockIdx.x * 256 + threadIdx.x;
  const int r = idx / NIN, c = idx % NIN;
  const int s = r >> 5, b = r & 31;
  const int bs = b * NS + s;
  float v;
  if (c < 32)      v = z[bs * 32 + c];
  else if (c < 48) v = cond[bs * 16 + (c - 32)];
  else             v = enc[(size_t)bs * NH + (c - 48)];
  x[idx] = v;
}

// ---------------------------------------------------------------------------
// MERGED 2-layer persistent LSTM == round-14 kernel (flag barrier, VGPR 116)
// with EXACTLY ONE change: both h stagings now use async
// __builtin_amdgcn_global_load_lds DMA into a single PACKED-u32 LDS plane
// (the h buffers are already packed hi|lo in global -> staging is a pure
// 98KB memcpy: no VGPR round-trip, no staging VALU, no write-side bank
// conflicts).  hi/lo bf16 fragments are extracted at read time (2 shifts
// per element, bit-identical values -> numerics unchanged).
// __syncthreads() drains vmcnt before its barrier (compiler-guaranteed), so
// the sync structure is identical to r14.
// ---------------------------------------------------------------------------
__global__ __launch_bounds__(LTHR)
__attribute__((amdgpu_waves_per_eu(2, 2)))
void lstm_merged(
    const float* __restrict__ xg0,   // [64*32][3072] layer-0 gates (biases folded)
    const float* __restrict__ Whh0,  // [3072][768]
    const float* __restrict__ Wih1,  // [3072][768]
    const float* __restrict__ Whh1,  // [3072][768]
    const float* __restrict__ bih1,  // [3072]
    const float* __restrict__ bhh1,  // [3072]
    const unsigned* __restrict__ hzero, // [32][768] packed zeros
    unsigned* h0pk,                  // [2048][768] packed bf16, row = t*32+b
    unsigned* h1pk,                  // [2048][768] packed bf16
    unsigned* flags) {               // 192 slots at stride 4 u32, zeroed
  extern __shared__ __align__(16) unsigned smem_u32[];
  unsigned* plane = smem_u32;                     // [32][HPW] packed h
  float*    gsp   = (float*)(smem_u32 + 32 * HPW); // [8][16][33]

  const int tid  = threadIdx.x;
  const int lane = tid & 63;
  const int wid  = tid >> 6;          // 0..7
  const bool wL1 = (wid >= 4);        // waves 4-7 compute layer-1 products
  const int kh   = wid & 3;           // K-quarter (k = kh*192 .. +192)
  const int lm   = lane & 15;
  const int lk   = lane >> 4;
  const int lblk = blockIdx.x;

  // resident Whh frags (L0 or L1 depending on wave -- same registers)
  const int grow = (lm >> 2) * NH + lblk * 4 + (lm & 3);  // gate-row (M=16)
  const float* WhhP = wL1 ? Whh1 : Whh0;
  bf16x8 whi[6], wlo[6];
  #pragma unroll
  for (int s6 = 0; s6 < 6; ++s6) {
    const float* wp = WhhP + (size_t)grow * NH + kh * 192 + s6 * 32 + lk * 8;
    float4 a = *(const float4*)wp;
    float4 b = *(const float4*)(wp + 4);
    float vv[8] = {a.x, a.y, a.z, a.w, b.x, b.y, b.z, b.w};
    #pragma unroll
    for (int i = 0; i < 8; ++i) {
      unsigned short h, l;
      split_bf16(vv[i], h, l);
      whi[s6][i] = (short)h;
      wlo[s6][i] = (short)l;
    }
  }

  // pointwise (tid<256): jp = tid>>5 in 0..7; jp<4 -> L0 cell, else L1
  const int jp = tid >> 5;
  const int bp = tid & 31;
  const bool pwL1 = (jp >= 4);
  const int jloc = jp & 3;
  float c_reg = 0.f;
  float bi = 0.f, bf_ = 0.f, bg = 0.f, bo = 0.f;
  if (tid < 256 && pwL1) {
    const int jj = lblk * 4 + jloc;
    bi  = bih1[0 * NH + jj] + bhh1[0 * NH + jj];
    bf_ = bih1[1 * NH + jj] + bhh1[1 * NH + jj];
    bg  = bih1[2 * NH + jj] + bhh1[2 * NH + jj];
    bo  = bih1[3 * NH + jj] + bhh1[3 * NH + jj];
  }

  for (int e = 0; e <= NS; ++e) {
    const unsigned* h0r = (e == 0) ? hzero : h0pk + (size_t)(e - 1) * NB * NH;
    const unsigned* h1r = (e <= 1) ? hzero : h1pk + (size_t)(e - 2) * NB * NH;
    // L0 xg prefetch (hides under staging/MFMA)
    float xgv0 = 0.f, xgv1 = 0.f, xgv2 = 0.f, xgv3 = 0.f;
    if (tid < 256 && !pwL1 && e < NS) {
      const float* xr = xg0 + (size_t)(e * NB + bp) * G4 + (lblk * 4 + jloc);
      xgv0 = xr[0]; xgv1 = xr[NH]; xgv2 = xr[2 * NH]; xgv3 = xr[3 * NH];
    }
    // ---- async-stage h0(e-1): consumed by L0 product AND L1 phase A ----
    async_stage(h0r, plane, wid, lane);
    __syncthreads();                 // vmcnt(0) drain + barrier
    f32x4 acc0 = {0.f, 0.f, 0.f, 0.f};
    f32x4 acc1 = {0.f, 0.f, 0.f, 0.f};
    if (!wL1) {
      // L0: gates = Whh0 . h0(e-1)
      #pragma unroll
      for (int s6 = 0; s6 < 6; ++s6) {
        const int kb = kh * 192 + s6 * 32 + lk * 8;
        bf16x8 bh0, bl0, bh1, bl1;
        read_frag(plane, lm * HPW + kb, bh0, bl0);
        read_frag(plane, (16 + lm) * HPW + kb, bh1, bl1);
        acc0 = __builtin_amdgcn_mfma_f32_16x16x32_bf16(whi[s6], bh0, acc0, 0, 0, 0);
        acc0 = __builtin_amdgcn_mfma_f32_16x16x32_bf16(whi[s6], bl0, acc0, 0, 0, 0);
        acc0 = __builtin_amdgcn_mfma_f32_16x16x32_bf16(wlo[s6], bh0, acc0, 0, 0, 0);
        acc1 = __builtin_amdgcn_mfma_f32_16x16x32_bf16(whi[s6], bh1, acc1, 0, 0, 0);
        acc1 = __builtin_amdgcn_mfma_f32_16x16x32_bf16(whi[s6], bl1, acc1, 0, 0, 0);
        acc1 = __builtin_amdgcn_mfma_f32_16x16x32_bf16(wlo[s6], bh1, acc1, 0, 0, 0);
      }
      #pragma unroll
      for (int r4 = 0; r4 < 4; ++r4) {
        gsp[wid * 528 + (lk * 4 + r4) * 33 + lm]      = acc0[r4];
        gsp[wid * 528 + (lk * 4 + r4) * 33 + 16 + lm] = acc1[r4];
      }
    } else {
      // L1 phase A: acc = Wih1 . h0(e-1)  (u-frags reloaded, L2-hot)
      #pragma unroll
      for (int s6 = 0; s6 < 6; ++s6) {
        const float* up = Wih1 + (size_t)grow * NH + kh * 192 + s6 * 32 + lk * 8;
        float4 ua = *(const float4*)up;
        float4 ub = *(const float4*)(up + 4);
        float uv[8] = {ua.x, ua.y, ua.z, ua.w, ub.x, ub.y, ub.z, ub.w};
        bf16x8 uh, ul;
        #pragma unroll
        for (int i = 0; i < 8; ++i) {
          unsigned short h, l;
          split_bf16(uv[i], h, l);
          uh[i] = (short)h;
          ul[i] = (short)l;
        }
        const int kb = kh * 192 + s6 * 32 + lk * 8;
        bf16x8 bh0, bl0, bh1, bl1;
        read_frag(plane, lm * HPW + kb, bh0, bl0);
        read_frag(plane, (16 + lm) * HPW + kb, bh1, bl1);
        acc0 = __builtin_amdgcn_mfma_f32_16x16x32_bf16(uh, bh0, acc0, 0, 0, 0);
        acc0 = __builtin_amdgcn_mfma_f32_16x16x32_bf16(uh, bl0, acc0, 0, 0, 0);
        acc0 = __builtin_amdgcn_mfma_f32_16x16x32_bf16(ul, bh0, acc0, 0, 0, 0);
        acc1 = __builtin_amdgcn_mfma_f32_16x16x32_bf16(uh, bh1, acc1, 0, 0, 0);
        acc1 = __builtin_amdgcn_mfma_f32_16x16x32_bf16(uh, bl1, acc1, 0, 0, 0);
        acc1 = __builtin_amdgcn_mfma_f32_16x16x32_bf16(ul, bh1, acc1, 0, 0, 0);
      }
    }
    __syncthreads();   // h0 reads done; plane free for h1
    // ---- async-stage h1(e-2), then L1 phase B ----
    async_stage(h1r, plane, wid, lane);
    __syncthreads();                 // vmcnt(0) drain + barrier
    if (wL1) {
      #pragma unroll
      for (int s6 = 0; s6 < 6; ++s6) {
        const int kb = kh * 192 + s6 * 32 + lk * 8;
        bf16x8 bh0, bl0, bh1, bl1;
        read_frag(plane, lm * HPW + kb, bh0, bl0);
        read_frag(plane, (16 + lm) * HPW + kb, bh1, bl1);
        acc0 = __builtin_amdgcn_mfma_f32_16x16x32_bf16(whi[s6], bh0, acc0, 0, 0, 0);
        acc0 = __builtin_amdgcn_mfma_f32_16x16x32_bf16(whi[s6], bl0, acc0, 0, 0, 0);
        acc0 = __builtin_amdgcn_mfma_f32_16x16x32_bf16(wlo[s6], bh0, acc0, 0, 0, 0);
        acc1 = __builtin_amdgcn_mfma_f32_16x16x32_bf16(whi[s6], bh1, acc1, 0, 0, 0);
        acc1 = __builtin_amdgcn_mfma_f32_16x16x32_bf16(whi[s6], bl1, acc1, 0, 0, 0);
        acc1 = __builtin_amdgcn_mfma_f32_16x16x32_bf16(wlo[s6], bh1, acc1, 0, 0, 0);
      }
      #pragma unroll
      for (int r4 = 0; r4 < 4; ++r4) {
        gsp[wid * 528 + (lk * 4 + r4) * 33 + lm]      = acc0[r4];
        gsp[wid * 528 + (lk * 4 + r4) * 33 + 16 + lm] = acc1[r4];
      }
    }
    __syncthreads();
    // ---- pointwise for both layers ----
    if (tid < 256) {
      if (!pwL1) {
        if (e < NS) {
          float sum[4];
          #pragma unroll
          for (int g = 0; g < 4; ++g) {
            const int row = g * 4 + jloc;
            sum[g] = gsp[0 * 528 + row * 33 + bp] + gsp[1 * 528 + row * 33 + bp] +
                     gsp[2 * 528 + row * 33 + bp] + gsp[3 * 528 + row * 33 + bp];
          }
          const float si = 1.f / (1.f + expf(-(sum[0] + xgv0)));
          const float sf = 1.f / (1.f + expf(-(sum[1] + xgv1)));
          const float so = 1.f / (1.f + expf(-(sum[3] + xgv3)));
          c_reg = sf * c_reg + si * tanhf(sum[2] + xgv2);
          const float hnew = so * tanhf(c_reg);
          unsigned short h16, l16;
          split_bf16(hnew, h16, l16);
          coh_store_u32(&h0pk[(size_t)(e * NB + bp) * NH + lblk * 4 + jloc],
                        ((unsigned)h16 << 16) | l16);
        }
      } else {
        if (e >= 1) {
          const int t = e - 1;
          float sum[4];
          #pragma unroll
          for (int g = 0; g < 4; ++g) {
            const int row = g * 4 + jloc;
            sum[g] = gsp[4 * 528 + row * 33 + bp] + gsp[5 * 528 + row * 33 + bp] +
                     gsp[6 * 528 + row * 33 + bp] + gsp[7 * 528 + row * 33 + bp];
          }
          const float si = 1.f / (1.f + expf(-(sum[0] + bi)));
          const float sf = 1.f / (1.f + expf(-(sum[1] + bf_)));
          const float so = 1.f / (1.f + expf(-(sum[3] + bo)));
          c_reg = sf * c_reg + si * tanhf(sum[2] + bg);
          const float hnew = so * tanhf(c_reg);
          unsigned short h16, l16;
          split_bf16(hnew, h16, l16);
          coh_store_u32(&h1pk[(size_t)(t * NB + bp) * NH + lblk * 4 + jloc],
                        ((unsigned)h16 << 16) | l16);
        }
      }
    }
    // ---- flag-array grid barrier (epochs 0..63; epoch 64 ends kernel) ----
    if (e < NS) {
      __syncthreads();                 // all waves' h stores issued
      if (tid == 0) {
        asm volatile("s_waitcnt vmcnt(0)" ::: "memory");
        __hip_atomic_store(&flags[(unsigned)blockIdx.x * 4], (unsigned)(e + 1),
                           __ATOMIC_RELAXED, __HIP_MEMORY_SCOPE_AGENT);
      }
      if (tid < FBLK) {
        while (__hip_atomic_load(&flags[(unsigned)tid * 4], __ATOMIC_RELAXED,
                                 __HIP_MEMORY_SCOPE_AGENT) < (unsigned)(e + 1))
          __builtin_amdgcn_s_sleep(1);
      }
      __syncthreads();
    }
  }
}

// ---------------------------------------------------------------------------
// preds[b*24+s] = dot(unpack(h1pk[s*32+b]), Wout) + bout
// ---------------------------------------------------------------------------
__global__ __launch_bounds__(64) void head_kernel(
    const unsigned* __restrict__ h1pk, const float* __restrict__ Wout,
    const float* __restrict__ bout, float* __restrict__ preds) {
  const int o = blockIdx.x;
  const int b = o / HOR_, s = o % HOR_;
  const int l = threadIdx.x;
  const unsigned* h = h1pk + (size_t)(s * NB + b) * NH;
  float acc = 0.f;
  #pragma unroll
  for (int k = l; k < NH; k += 64) {
    const unsigned w = h[k];
    const float v = __uint_as_float(w & 0xffff0000u) + __uint_as_float(w << 16);
    acc += v * Wout[k];
  }
  #pragma unroll
  for (int m = 32; m; m >>= 1) acc += __shfl_xor(acc, m);
  if (l == 0) preds[o] = acc + bout[0];
}

// ---------------------------------------------------------------------------
extern "C" void kernel_launch(void* const* d_in, const int* in_sizes, int n_in,
                              void* d_out, int out_size, void* d_ws, size_t ws_size,
                              hipStream_t stream) {
  const float* z    = (const float*)d_in[0];
  const float* cond = (const float*)d_in[1];
  const float* encs = (const float*)d_in[2];
  const float* W1   = (const float*)d_in[4];
  const float* b1   = (const float*)d_in[5];
  const float* W2   = (const float*)d_in[6];
  const float* b2   = (const float*)d_in[7];
  const float* Wih0 = (const float*)d_in[8];
  const float* Whh0 = (const float*)d_in[9];
  const float* bih0 = (const float*)d_in[10];
  const float* bhh0 = (const float*)d_in[11];
  const float* Wih1 = (const float*)d_in[12];
  const float* Whh1 = (const float*)d_in[13];
  const float* bih1 = (const float*)d_in[14];
  const float* bhh1 = (const float*)d_in[15];
  const float* Wout = (const float*)d_in[16];
  const float* bout = (const float*)d_in[17];

  float* out     = (float*)d_out;
  float* preds   = out;
  float* enc_out = out + NB * HOR_;

  float* ws    = (float*)d_ws;
  float* xb    = ws + OFF_X;
  float* mean  = ws + OFF_MEAN;
  float* tmp   = ws + OFF_TMP;
  unsigned* h0pk = (unsigned*)(ws + OFF_H0PK);
  unsigned* h1pk = (unsigned*)(ws + OFF_H1PK);
  float* xg    = ws + OFF_XG;
  unsigned* hzero = (unsigned*)(ws + OFF_HZERO);
  unsigned* flags = (unsigned*)(ws + OFF_FLG);

  // allow >64KB dynamic LDS for the persistent kernel
  (void)hipFuncSetAttribute(reinterpret_cast<const void*>(lstm_merged),
                            hipFuncAttributeMaxDynamicSharedMemorySize,
                            160 * 1024);

  // 1. segment mean (filter and mean are linear and commute -> pool first)
  seg_mean_kernel<<<NSEG_, 192, 0, stream>>>(encs, mean);
  // 2. encoded = (mean @ W1^T + b1) @ W2^T + b2 -> straight into d_out (MFMA)
  gemm_mfma_nt<<<dim3(NH / 64, NSEG_ / 64), 256, 0, stream>>>(
      mean, W1, b1, nullptr, tmp, NSEG_, NH, NH);
  gemm_mfma_nt<<<dim3(NH / 64, NSEG_ / 64), 256, 0, stream>>>(
      tmp, W2, b2, nullptr, enc_out, NSEG_, NH, NH);
  // 3. x = concat(z, cond, encoded), time-major rows (s*32+b)
  build_x_kernel<<<(NSEG_ * NIN) / 256, 256, 0, stream>>>(z, cond, enc_out, xb);
  // 4. layer-0 input gates (biases folded in), K=816 (guarded chunks)
  gemm_mfma_nt<<<dim3(G4 / 64, NSEG_ / 64), 256, 0, stream>>>(
      xb, Wih0, bih0, bhh0, xg, NSEG_, G4, NIN);
  // 5. merged, pipelined 2-layer recurrence (layer-1 xg GEMM folded in)
  hipMemsetAsync(hzero, 0, (size_t)(SZ_HZERO + 1024) * sizeof(float), stream);
  lstm_merged<<<FBLK, LTHR, SMEM_BYTES, stream>>>(
      xg, Whh0, Wih1, Whh1, bih1, bhh1, hzero, h0pk, h1pk, flags);
  // 6. head
  head_kernel<<<NB * HOR_, 64, 0, stream>>>(h1pk, Wout, bout, preds);
}

// Round 16
// 637.293 us; speedup vs baseline: 1.0776x; 1.0776x over previous
//
#include <hip/hip_runtime.h>
#include <cstddef>

#define NB 32
#define NS 64
#define NH 768
#define NSEG_ (NB*NS)      // 2048
#define NIN 816
#define G4 3072
#define HOR_ 24
#define FBLK 192           // merged blocks: each owns 4 j of L0 + 4 j of L1
#define LTHR 512           // 8 waves/block

// MFMA fragment types (short-based bf16, compile-verified on gfx950)
typedef __attribute__((ext_vector_type(8))) short bf16x8;
typedef __attribute__((ext_vector_type(4))) float f32x4;
typedef __attribute__((ext_vector_type(8))) unsigned short u16x8;

// lstm dynamic-LDS: TWO bf16 h planes [32][776 u16] + partial-C [8][16][33]
#define HP2 776            // plane row stride in u16 (768 + 8 pad; 16B-aligned)
#define SMEM_BYTES (2*32*HP2*2 + 8*528*4)   // 99328 + 16896 = 116224

// workspace offsets (floats / u32s)
#define OFF_X      0
#define SZ_X       (NSEG_*NIN)
#define OFF_MEAN   (OFF_X + SZ_X)
#define SZ_MEAN    (NSEG_*NH)
#define OFF_TMP    (OFF_MEAN + SZ_MEAN)
#define OFF_H0PK   (OFF_TMP + SZ_MEAN)      // [2048][768] packed bf16 hi|lo
#define OFF_H1PK   (OFF_H0PK + SZ_MEAN)
#define OFF_XG     (OFF_H1PK + SZ_MEAN)
#define SZ_XG      (NSEG_*G4)
#define OFF_HZERO  (OFF_XG + SZ_XG)
#define SZ_HZERO   (NB*NH)
#define OFF_FLG    (OFF_HZERO + SZ_HZERO)   // 192 flag slots, 16B apart

// agent-scope write-through store (coherence point; proven r6)
__device__ __forceinline__ void coh_store_u32(unsigned* p, unsigned v) {
  __hip_atomic_store(p, v, __ATOMIC_RELAXED, __HIP_MEMORY_SCOPE_AGENT);
}

// split a float into RNE bf16 hi + bf16 residual (RNE hi halves the h
// quantization error when the recurrence consumes hi alone; hi+lo still
// reconstructs ~fp32 for the GEMM path and the head)
__device__ __forceinline__ void split_bf16(float v, unsigned short& hi,
                                           unsigned short& lo) {
  const unsigned u = __float_as_uint(v);
  const unsigned r = u + 0x7FFFu + ((u >> 16) & 1u);   // round-to-nearest-even
  hi = (unsigned short)(r >> 16);
  const float rem = v - __uint_as_float((r >> 16) << 16);
  lo = (unsigned short)(__float_as_uint(rem) >> 16);
}

// stage the bf16-hi plane from packed-u32 global h (1 shift per element)
__device__ __forceinline__ void stage_hi(const unsigned* __restrict__ src,
                                         unsigned short* plane, int sb, int sch) {
  #pragma unroll
  for (int it = 0; it < 6; ++it) {
    const int k0 = (sch + it * 16) * 8;
    uint4 wa = *(const uint4*)(src + (size_t)sb * NH + k0);
    uint4 wb = *(const uint4*)(src + (size_t)sb * NH + k0 + 4);
    unsigned ww[8] = {wa.x, wa.y, wa.z, wa.w, wb.x, wb.y, wb.z, wb.w};
    u16x8 HI;
    #pragma unroll
    for (int i = 0; i < 8; ++i) HI[i] = (unsigned short)(ww[i] >> 16);
    *(u16x8*)(&plane[sb * HP2 + k0]) = HI;
  }
}

// ---------------------------------------------------------------------------
// Segment mean: encs [65536,768] -> mean [2048,768]
// ---------------------------------------------------------------------------
__global__ __launch_bounds__(192) void seg_mean_kernel(
    const float* __restrict__ encs, float* __restrict__ mean) {
  const int s = blockIdx.x;
  const int t = threadIdx.x;
  const float4* base = (const float4*)(encs + (size_t)s * 32 * NH);
  float4 a = {0.f, 0.f, 0.f, 0.f};
  #pragma unroll 4
  for (int r = 0; r < 32; ++r) {
    float4 v = base[(size_t)r * (NH / 4) + t];
    a.x += v.x; a.y += v.y; a.z += v.z; a.w += v.w;
  }
  const float inv = 1.f / 32.f;
  float4 o = {a.x * inv, a.y * inv, a.z * inv, a.w * inv};
  ((float4*)mean)[(size_t)s * (NH / 4) + t] = o;
}

// ---------------------------------------------------------------------------
// Split-bf16 MFMA GEMM: C[M,N] = A[M,K] @ W[N,K]^T + bias1[n] + bias2[n]
// (round-10 proven: ~fp32 accuracy via hi.hi + hi.lo + lo.hi)
// ---------------------------------------------------------------------------
__global__ __launch_bounds__(256) void gemm_mfma_nt(
    const float* __restrict__ A, const float* __restrict__ W,
    const float* __restrict__ bias1, const float* __restrict__ bias2,
    float* __restrict__ C, int M, int N, int K) {
  __shared__ unsigned short Ahi[64 * 40];
  __shared__ unsigned short Alo[64 * 40];
  __shared__ unsigned short Whi[64 * 40];
  __shared__ unsigned short Wlo[64 * 40];
  const int tid = threadIdx.x;
  const int bm = blockIdx.y, bn = blockIdx.x;
  const int lane = tid & 63;
  const int wid  = tid >> 6;
  const int lm = lane & 15;
  const int lk = lane >> 4;
  const int srow = tid >> 2;
  const int skc  = (tid & 3) * 8;

  const float* Ap = A + (size_t)(bm * 64 + srow) * K;
  const float* Wp = W + (size_t)(bn * 64 + srow) * K;

  f32x4 acc[4];
  #pragma unroll
  for (int nf = 0; nf < 4; ++nf) acc[nf] = (f32x4){0.f, 0.f, 0.f, 0.f};

  for (int k0 = 0; k0 < K; k0 += 32) {
    float va[8], vw[8];
    if (k0 + skc + 8 <= K) {
      float4 a0 = *(const float4*)(Ap + k0 + skc);
      float4 a1 = *(const float4*)(Ap + k0 + skc + 4);
      float4 w0 = *(const float4*)(Wp + k0 + skc);
      float4 w1 = *(const float4*)(Wp + k0 + skc + 4);
      va[0]=a0.x; va[1]=a0.y; va[2]=a0.z; va[3]=a0.w;
      va[4]=a1.x; va[5]=a1.y; va[6]=a1.z; va[7]=a1.w;
      vw[0]=w0.x; vw[1]=w0.y; vw[2]=w0.z; vw[3]=w0.w;
      vw[4]=w1.x; vw[5]=w1.y; vw[6]=w1.z; vw[7]=w1.w;
    } else {
      #pragma unroll
      for (int i = 0; i < 8; ++i) { va[i] = 0.f; vw[i] = 0.f; }
    }
    u16x8 AH, AL, WH, WL;
    #pragma unroll
    for (int i = 0; i < 8; ++i) {
      unsigned short h, l;
      split_bf16(va[i], h, l); AH[i] = h; AL[i] = l;
      split_bf16(vw[i], h, l); WH[i] = h; WL[i] = l;
    }
    __syncthreads();
    *(u16x8*)(&Ahi[srow * 40 + skc]) = AH;
    *(u16x8*)(&Alo[srow * 40 + skc]) = AL;
    *(u16x8*)(&Whi[srow * 40 + skc]) = WH;
    *(u16x8*)(&Wlo[srow * 40 + skc]) = WL;
    __syncthreads();
    bf16x8 ah = *(bf16x8*)(&Ahi[(wid * 16 + lm) * 40 + lk * 8]);
    bf16x8 al = *(bf16x8*)(&Alo[(wid * 16 + lm) * 40 + lk * 8]);
    #pragma unroll
    for (int nf = 0; nf < 4; ++nf) {
      bf16x8 bh = *(bf16x8*)(&Whi[(nf * 16 + lm) * 40 + lk * 8]);
      bf16x8 bl = *(bf16x8*)(&Wlo[(nf * 16 + lm) * 40 + lk * 8]);
      acc[nf] = __builtin_amdgcn_mfma_f32_16x16x32_bf16(ah, bh, acc[nf], 0, 0, 0);
      acc[nf] = __builtin_amdgcn_mfma_f32_16x16x32_bf16(ah, bl, acc[nf], 0, 0, 0);
      acc[nf] = __builtin_amdgcn_mfma_f32_16x16x32_bf16(al, bh, acc[nf], 0, 0, 0);
    }
  }
  #pragma unroll
  for (int nf = 0; nf < 4; ++nf) {
    const int gn = bn * 64 + nf * 16 + lm;
    float bb = 0.f;
    if (bias1) bb += bias1[gn];
    if (bias2) bb += bias2[gn];
    #pragma unroll
    for (int r4 = 0; r4 < 4; ++r4) {
      const int gm = bm * 64 + wid * 16 + lk * 4 + r4;
      C[(size_t)gm * N + gn] = acc[nf][r4] + bb;
    }
  }
}

// ---------------------------------------------------------------------------
// x[s*32+b][0:816] = concat(z[b,s], cond[b,s], encoded[b*64+s])
// ---------------------------------------------------------------------------
__global__ __launch_bounds__(256) void build_x_kernel(
    const float* __restrict__ z, const float* __restrict__ cond,
    const float* __restrict__ enc, float* __restrict__ x) {
  const int idx = blockIdx.x * 256 + threadIdx.x;
  const int r = idx / NIN, c = idx % NIN;
  const int s = r >> 5, b = r & 31;
  const int bs = b * NS + s;
  float v;
  if (c < 32)      v = z[bs * 32 + c];
  else if (c < 48) v = cond[bs * 16 + (c - 32)];
  else             v = enc[(size_t)bs * NH + (c - 48)];
  x[idx] = v;
}

// ---------------------------------------------------------------------------
// MERGED 2-layer persistent LSTM (r14 flag-barrier base) with ONE structural
// change: the recurrence h OPERAND is bf16-only (RNE hi half), so BOTH h
// planes (h0 and h1, 49.7KB each) fit in LDS simultaneously.  Both stagings
// issue at epoch top (LLC RTs overlap), one sync replaces three, and MFMA is
// 2 products (whi.b + wlo.b -- weights keep full hi/lo precision).  B-frags
// are direct ds_read_b128 (zero unpack VALU).  Global h exchange stays
// packed hi|lo u32 (GEMM path and head keep ~fp32 h).  Barrier, coherence,
// pointwise byte-identical to r14.
// ---------------------------------------------------------------------------
__global__ __launch_bounds__(LTHR)
__attribute__((amdgpu_waves_per_eu(2, 2)))
void lstm_merged(
    const float* __restrict__ xg0,   // [64*32][3072] layer-0 gates (biases folded)
    const float* __restrict__ Whh0,  // [3072][768]
    const float* __restrict__ Wih1,  // [3072][768]
    const float* __restrict__ Whh1,  // [3072][768]
    const float* __restrict__ bih1,  // [3072]
    const float* __restrict__ bhh1,  // [3072]
    const unsigned* __restrict__ hzero, // [32][768] packed zeros
    unsigned* h0pk,                  // [2048][768] packed bf16, row = t*32+b
    unsigned* h1pk,                  // [2048][768] packed bf16
    unsigned* flags) {               // 192 slots at stride 4 u32, zeroed
  extern __shared__ __align__(16) unsigned short smem_us[];
  unsigned short* pA  = smem_us;                 // [32][HP2] bf16(h0)
  unsigned short* pB  = smem_us + 32 * HP2;      // [32][HP2] bf16(h1)
  float*          gsp = (float*)(smem_us + 2 * 32 * HP2);  // [8][16][33]

  const int tid  = threadIdx.x;
  const int lane = tid & 63;
  const int wid  = tid >> 6;          // 0..7
  const bool wL1 = (wid >= 4);        // waves 4-7 compute layer-1 products
  const int kh   = wid & 3;           // K-quarter (k = kh*192 .. +192)
  const int lm   = lane & 15;
  const int lk   = lane >> 4;
  const int lblk = blockIdx.x;

  // resident Whh frags (L0 or L1 depending on wave -- same registers)
  const int grow = (lm >> 2) * NH + lblk * 4 + (lm & 3);  // gate-row (M=16)
  const float* WhhP = wL1 ? Whh1 : Whh0;
  bf16x8 whi[6], wlo[6];
  #pragma unroll
  for (int s6 = 0; s6 < 6; ++s6) {
    const float* wp = WhhP + (size_t)grow * NH + kh * 192 + s6 * 32 + lk * 8;
    float4 a = *(const float4*)wp;
    float4 b = *(const float4*)(wp + 4);
    float vv[8] = {a.x, a.y, a.z, a.w, b.x, b.y, b.z, b.w};
    #pragma unroll
    for (int i = 0; i < 8; ++i) {
      unsigned short h, l;
      split_bf16(vv[i], h, l);
      whi[s6][i] = (short)h;
      wlo[s6][i] = (short)l;
    }
  }

  // pointwise (tid<256): jp = tid>>5 in 0..7; jp<4 -> L0 cell, else L1
  const int jp = tid >> 5;
  const int bp = tid & 31;
  const bool pwL1 = (jp >= 4);
  const int jloc = jp & 3;
  float c_reg = 0.f;
  float bi = 0.f, bf_ = 0.f, bg = 0.f, bo = 0.f;
  if (tid < 256 && pwL1) {
    const int jj = lblk * 4 + jloc;
    bi  = bih1[0 * NH + jj] + bhh1[0 * NH + jj];
    bf_ = bih1[1 * NH + jj] + bhh1[1 * NH + jj];
    bg  = bih1[2 * NH + jj] + bhh1[2 * NH + jj];
    bo  = bih1[3 * NH + jj] + bhh1[3 * NH + jj];
  }
  const int sb  = tid >> 4;          // staging batch 0..31
  const int sch = tid & 15;          // staging chunk

  for (int e = 0; e <= NS; ++e) {
    const unsigned* h0r = (e == 0) ? hzero : h0pk + (size_t)(e - 1) * NB * NH;
    const unsigned* h1r = (e <= 1) ? hzero : h1pk + (size_t)(e - 2) * NB * NH;
    // L0 xg prefetch (hides under staging/MFMA)
    float xgv0 = 0.f, xgv1 = 0.f, xgv2 = 0.f, xgv3 = 0.f;
    if (tid < 256 && !pwL1 && e < NS) {
      const float* xr = xg0 + (size_t)(e * NB + bp) * G4 + (lblk * 4 + jloc);
      xgv0 = xr[0]; xgv1 = xr[NH]; xgv2 = xr[2 * NH]; xgv3 = xr[3 * NH];
    }
    // ---- stage BOTH planes at epoch top: LLC round-trips overlap ----
    stage_hi(h0r, pA, sb, sch);
    stage_hi(h1r, pB, sb, sch);
    __syncthreads();
    f32x4 acc0 = {0.f, 0.f, 0.f, 0.f};
    f32x4 acc1 = {0.f, 0.f, 0.f, 0.f};
    if (!wL1) {
      // L0: gates = Whh0 . h0(e-1)   (2 products: weight hi + weight lo)
      #pragma unroll
      for (int s6 = 0; s6 < 6; ++s6) {
        const int kb = kh * 192 + s6 * 32 + lk * 8;
        bf16x8 b0 = *(bf16x8*)(&pA[lm * HP2 + kb]);
        bf16x8 b1 = *(bf16x8*)(&pA[(16 + lm) * HP2 + kb]);
        acc0 = __builtin_amdgcn_mfma_f32_16x16x32_bf16(whi[s6], b0, acc0, 0, 0, 0);
        acc0 = __builtin_amdgcn_mfma_f32_16x16x32_bf16(wlo[s6], b0, acc0, 0, 0, 0);
        acc1 = __builtin_amdgcn_mfma_f32_16x16x32_bf16(whi[s6], b1, acc1, 0, 0, 0);
        acc1 = __builtin_amdgcn_mfma_f32_16x16x32_bf16(wlo[s6], b1, acc1, 0, 0, 0);
      }
    } else {
      // L1 phase A: acc = Wih1 . h0(e-1)  (u-frags reloaded, L2-hot)
      #pragma unroll
      for (int s6 = 0; s6 < 6; ++s6) {
        const float* up = Wih1 + (size_t)grow * NH + kh * 192 + s6 * 32 + lk * 8;
        float4 ua = *(const float4*)up;
        float4 ub = *(const float4*)(up + 4);
        float uv[8] = {ua.x, ua.y, ua.z, ua.w, ub.x, ub.y, ub.z, ub.w};
        bf16x8 uh, ul;
        #pragma unroll
        for (int i = 0; i < 8; ++i) {
          unsigned short h, l;
          split_bf16(uv[i], h, l);
          uh[i] = (short)h;
          ul[i] = (short)l;
        }
        const int kb = kh * 192 + s6 * 32 + lk * 8;
        bf16x8 b0 = *(bf16x8*)(&pA[lm * HP2 + kb]);
        bf16x8 b1 = *(bf16x8*)(&pA[(16 + lm) * HP2 + kb]);
        acc0 = __builtin_amdgcn_mfma_f32_16x16x32_bf16(uh, b0, acc0, 0, 0, 0);
        acc0 = __builtin_amdgcn_mfma_f32_16x16x32_bf16(ul, b0, acc0, 0, 0, 0);
        acc1 = __builtin_amdgcn_mfma_f32_16x16x32_bf16(uh, b1, acc1, 0, 0, 0);
        acc1 = __builtin_amdgcn_mfma_f32_16x16x32_bf16(ul, b1, acc1, 0, 0, 0);
      }
      // L1 phase B: acc += Whh1 . h1(e-2)  (resident frags, plane B)
      #pragma unroll
      for (int s6 = 0; s6 < 6; ++s6) {
        const int kb = kh * 192 + s6 * 32 + lk * 8;
        bf16x8 b0 = *(bf16x8*)(&pB[lm * HP2 + kb]);
        bf16x8 b1 = *(bf16x8*)(&pB[(16 + lm) * HP2 + kb]);
        acc0 = __builtin_amdgcn_mfma_f32_16x16x32_bf16(whi[s6], b0, acc0, 0, 0, 0);
        acc0 = __builtin_amdgcn_mfma_f32_16x16x32_bf16(wlo[s6], b0, acc0, 0, 0, 0);
        acc1 = __builtin_amdgcn_mfma_f32_16x16x32_bf16(whi[s6], b1, acc1, 0, 0, 0);
        acc1 = __builtin_amdgcn_mfma_f32_16x16x32_bf16(wlo[s6], b1, acc1, 0, 0, 0);
      }
    }
    #pragma unroll
    for (int r4 = 0; r4 < 4; ++r4) {
      gsp[wid * 528 + (lk * 4 + r4) * 33 + lm]      = acc0[r4];
      gsp[wid * 528 + (lk * 4 + r4) * 33 + 16 + lm] = acc1[r4];
    }
    __syncthreads();
    // ---- pointwise for both layers ----
    if (tid < 256) {
      if (!pwL1) {
        if (e < NS) {
          float sum[4];
          #pragma unroll
          for (int g = 0; g < 4; ++g) {
            const int row = g * 4 + jloc;
            sum[g] = gsp[0 * 528 + row * 33 + bp] + gsp[1 * 528 + row * 33 + bp] +
                     gsp[2 * 528 + row * 33 + bp] + gsp[3 * 528 + row * 33 + bp];
          }
          const float si = 1.f / (1.f + expf(-(sum[0] + xgv0)));
          const float sf = 1.f / (1.f + expf(-(sum[1] + xgv1)));
          const float so = 1.f / (1.f + expf(-(sum[3] + xgv3)));
          c_reg = sf * c_reg + si * tanhf(sum[2] + xgv2);
          const float hnew = so * tanhf(c_reg);
          unsigned short h16, l16;
          split_bf16(hnew, h16, l16);
          coh_store_u32(&h0pk[(size_t)(e * NB + bp) * NH + lblk * 4 + jloc],
                        ((unsigned)h16 << 16) | l16);
        }
      } else {
        if (e >= 1) {
          const int t = e - 1;
          float sum[4];
          #pragma unroll
          for (int g = 0; g < 4; ++g) {
            const int row = g * 4 + jloc;
            sum[g] = gsp[4 * 528 + row * 33 + bp] + gsp[5 * 528 + row * 33 + bp] +
                     gsp[6 * 528 + row * 33 + bp] + gsp[7 * 528 + row * 33 + bp];
          }
          const float si = 1.f / (1.f + expf(-(sum[0] + bi)));
          const float sf = 1.f / (1.f + expf(-(sum[1] + bf_)));
          const float so = 1.f / (1.f + expf(-(sum[3] + bo)));
          c_reg = sf * c_reg + si * tanhf(sum[2] + bg);
          const float hnew = so * tanhf(c_reg);
          unsigned short h16, l16;
          split_bf16(hnew, h16, l16);
          coh_store_u32(&h1pk[(size_t)(t * NB + bp) * NH + lblk * 4 + jloc],
                        ((unsigned)h16 << 16) | l16);
        }
      }
    }
    // ---- flag-array grid barrier (epochs 0..63; epoch 64 ends kernel) ----
    if (e < NS) {
      __syncthreads();                 // all waves' h stores issued
      if (tid == 0) {
        asm volatile("s_waitcnt vmcnt(0)" ::: "memory");
        __hip_atomic_store(&flags[(unsigned)blockIdx.x * 4], (unsigned)(e + 1),
                           __ATOMIC_RELAXED, __HIP_MEMORY_SCOPE_AGENT);
      }
      if (tid < FBLK) {
        while (__hip_atomic_load(&flags[(unsigned)tid * 4], __ATOMIC_RELAXED,
                                 __HIP_MEMORY_SCOPE_AGENT) < (unsigned)(e + 1))
          __builtin_amdgcn_s_sleep(1);
      }
      __syncthreads();
    }
  }
}

// ---------------------------------------------------------------------------
// preds[b*24+s] = dot(unpack(h1pk[s*32+b]), Wout) + bout
// ---------------------------------------------------------------------------
__global__ __launch_bounds__(64) void head_kernel(
    const unsigned* __restrict__ h1pk, const float* __restrict__ Wout,
    const float* __restrict__ bout, float* __restrict__ preds) {
  const int o = blockIdx.x;
  const int b = o / HOR_, s = o % HOR_;
  const int l = threadIdx.x;
  const unsigned* h = h1pk + (size_t)(s * NB + b) * NH;
  float acc = 0.f;
  #pragma unroll
  for (int k = l; k < NH; k += 64) {
    const unsigned w = h[k];
    const float v = __uint_as_float(w & 0xffff0000u) + __uint_as_float(w << 16);
    acc += v * Wout[k];
  }
  #pragma unroll
  for (int m = 32; m; m >>= 1) acc += __shfl_xor(acc, m);
  if (l == 0) preds[o] = acc + bout[0];
}

// ---------------------------------------------------------------------------
extern "C" void kernel_launch(void* const* d_in, const int* in_sizes, int n_in,
                              void* d_out, int out_size, void* d_ws, size_t ws_size,
                              hipStream_t stream) {
  const float* z    = (const float*)d_in[0];
  const float* cond = (const float*)d_in[1];
  const float* encs = (const float*)d_in[2];
  const float* W1   = (const float*)d_in[4];
  const float* b1   = (const float*)d_in[5];
  const float* W2   = (const float*)d_in[6];
  const float* b2   = (const float*)d_in[7];
  const float* Wih0 = (const float*)d_in[8];
  const float* Whh0 = (const float*)d_in[9];
  const float* bih0 = (const float*)d_in[10];
  const float* bhh0 = (const float*)d_in[11];
  const float* Wih1 = (const float*)d_in[12];
  const float* Whh1 = (const float*)d_in[13];
  const float* bih1 = (const float*)d_in[14];
  const float* bhh1 = (const float*)d_in[15];
  const float* Wout = (const float*)d_in[16];
  const float* bout = (const float*)d_in[17];

  float* out     = (float*)d_out;
  float* preds   = out;
  float* enc_out = out + NB * HOR_;

  float* ws    = (float*)d_ws;
  float* xb    = ws + OFF_X;
  float* mean  = ws + OFF_MEAN;
  float* tmp   = ws + OFF_TMP;
  unsigned* h0pk = (unsigned*)(ws + OFF_H0PK);
  unsigned* h1pk = (unsigned*)(ws + OFF_H1PK);
  float* xg    = ws + OFF_XG;
  unsigned* hzero = (unsigned*)(ws + OFF_HZERO);
  unsigned* flags = (unsigned*)(ws + OFF_FLG);

  // allow >64KB dynamic LDS for the persistent kernel
  (void)hipFuncSetAttribute(reinterpret_cast<const void*>(lstm_merged),
                            hipFuncAttributeMaxDynamicSharedMemorySize,
                            160 * 1024);

  // 1. segment mean (filter and mean are linear and commute -> pool first)
  seg_mean_kernel<<<NSEG_, 192, 0, stream>>>(encs, mean);
  // 2. encoded = (mean @ W1^T + b1) @ W2^T + b2 -> straight into d_out (MFMA)
  gemm_mfma_nt<<<dim3(NH / 64, NSEG_ / 64), 256, 0, stream>>>(
      mean, W1, b1, nullptr, tmp, NSEG_, NH, NH);
  gemm_mfma_nt<<<dim3(NH / 64, NSEG_ / 64), 256, 0, stream>>>(
      tmp, W2, b2, nullptr, enc_out, NSEG_, NH, NH);
  // 3. x = concat(z, cond, encoded), time-major rows (s*32+b)
  build_x_kernel<<<(NSEG_ * NIN) / 256, 256, 0, stream>>>(z, cond, enc_out, xb);
  // 4. layer-0 input gates (biases folded in), K=816 (guarded chunks)
  gemm_mfma_nt<<<dim3(G4 / 64, NSEG_ / 64), 256, 0, stream>>>(
      xb, Wih0, bih0, bhh0, xg, NSEG_, G4, NIN);
  // 5. merged, pipelined 2-layer recurrence (layer-1 xg GEMM folded in)
  hipMemsetAsync(hzero, 0, (size_t)(SZ_HZERO + 1024) * sizeof(float), stream);
  lstm_merged<<<FBLK, LTHR, SMEM_BYTES, stream>>>(
      xg, Whh0, Wih1, Whh1, bih1, bhh1, hzero, h0pk, h1pk, flags);
  // 6. head
  head_kernel<<<NB * HOR_, 64, 0, stream>>>(h1pk, Wout, bout, preds);
}

// Round 17
// 582.547 us; speedup vs baseline: 1.1789x; 1.0940x over previous
//
#include <hip/hip_runtime.h>
#include <cstddef>

#define NB 32
#define NS 64
#define NH 768
#define NSEG_ (NB*NS)      // 2048
#define NIN 816
#define G4 3072
#define HOR_ 24
#define FBLK 192           // merged blocks: each owns 4 j of L0 + 4 j of L1
#define LTHR 512           // 8 waves/block

// MFMA fragment types (short-based bf16, compile-verified on gfx950)
typedef __attribute__((ext_vector_type(8))) short bf16x8;
typedef __attribute__((ext_vector_type(4))) float f32x4;
typedef __attribute__((ext_vector_type(8))) unsigned short u16x8;

// lstm dynamic-LDS: TWO bf16 h planes [32][776 u16] + partial-C [8][16][33]
#define HP2 776            // plane row stride in u16 (768 + 8 pad; 16B-aligned)
#define SMEM_BYTES (2*32*HP2*2 + 8*528*4)   // 99328 + 16896 = 116224

// workspace offsets (floats)
#define OFF_X      0
#define SZ_X       (NSEG_*NIN)
#define OFF_MEAN   (OFF_X + SZ_X)
#define SZ_MEAN    (NSEG_*NH)
#define OFF_TMP    (OFF_MEAN + SZ_MEAN)
#define OFF_H0PK   (OFF_TMP + SZ_MEAN)      // [2048][768] bf16 u16 (half used)
#define OFF_H1PK   (OFF_H0PK + SZ_MEAN)
#define OFF_XG     (OFF_H1PK + SZ_MEAN)
#define SZ_XG      (NSEG_*G4)
#define OFF_HZERO  (OFF_XG + SZ_XG)
#define SZ_HZERO   (NB*NH)
#define OFF_FLG    (OFF_HZERO + SZ_HZERO)   // 192 flag slots, 16B apart

// agent-scope write-through stores (coherence point; proven r6)
__device__ __forceinline__ void coh_store_u16(unsigned short* p, unsigned short v) {
  __hip_atomic_store(p, v, __ATOMIC_RELAXED, __HIP_MEMORY_SCOPE_AGENT);
}

// split a float into RNE bf16 hi + bf16 residual (GEMM path)
__device__ __forceinline__ void split_bf16(float v, unsigned short& hi,
                                           unsigned short& lo) {
  const unsigned u = __float_as_uint(v);
  const unsigned r = u + 0x7FFFu + ((u >> 16) & 1u);   // round-to-nearest-even
  hi = (unsigned short)(r >> 16);
  const float rem = v - __uint_as_float((r >> 16) << 16);
  lo = (unsigned short)(__float_as_uint(rem) >> 16);
}

// RNE bf16 only (recurrence h store)
__device__ __forceinline__ unsigned short rne_bf16(float v) {
  const unsigned u = __float_as_uint(v);
  return (unsigned short)((u + 0x7FFFu + ((u >> 16) & 1u)) >> 16);
}

// stage bf16 h [32][768] u16 global -> LDS plane: pure 16B copies, no VALU
__device__ __forceinline__ void stage_hi(const unsigned short* __restrict__ src,
                                         unsigned short* plane, int sb, int sch) {
  #pragma unroll
  for (int it = 0; it < 6; ++it) {
    const int k0 = (sch + it * 16) * 8;
    uint4 v = *(const uint4*)(src + (size_t)sb * NH + k0);
    *(uint4*)(&plane[sb * HP2 + k0]) = v;
  }
}

// ---------------------------------------------------------------------------
// Segment mean: encs [65536,768] -> mean [2048,768]
// ---------------------------------------------------------------------------
__global__ __launch_bounds__(192) void seg_mean_kernel(
    const float* __restrict__ encs, float* __restrict__ mean) {
  const int s = blockIdx.x;
  const int t = threadIdx.x;
  const float4* base = (const float4*)(encs + (size_t)s * 32 * NH);
  float4 a = {0.f, 0.f, 0.f, 0.f};
  #pragma unroll 4
  for (int r = 0; r < 32; ++r) {
    float4 v = base[(size_t)r * (NH / 4) + t];
    a.x += v.x; a.y += v.y; a.z += v.z; a.w += v.w;
  }
  const float inv = 1.f / 32.f;
  float4 o = {a.x * inv, a.y * inv, a.z * inv, a.w * inv};
  ((float4*)mean)[(size_t)s * (NH / 4) + t] = o;
}

// ---------------------------------------------------------------------------
// Split-bf16 MFMA GEMM: C[M,N] = A[M,K] @ W[N,K]^T + bias1[n] + bias2[n]
// (round-10 proven: ~fp32 accuracy via hi.hi + hi.lo + lo.hi)
// ---------------------------------------------------------------------------
__global__ __launch_bounds__(256) void gemm_mfma_nt(
    const float* __restrict__ A, const float* __restrict__ W,
    const float* __restrict__ bias1, const float* __restrict__ bias2,
    float* __restrict__ C, int M, int N, int K) {
  __shared__ unsigned short Ahi[64 * 40];
  __shared__ unsigned short Alo[64 * 40];
  __shared__ unsigned short Whi[64 * 40];
  __shared__ unsigned short Wlo[64 * 40];
  const int tid = threadIdx.x;
  const int bm = blockIdx.y, bn = blockIdx.x;
  const int lane = tid & 63;
  const int wid  = tid >> 6;
  const int lm = lane & 15;
  const int lk = lane >> 4;
  const int srow = tid >> 2;
  const int skc  = (tid & 3) * 8;

  const float* Ap = A + (size_t)(bm * 64 + srow) * K;
  const float* Wp = W + (size_t)(bn * 64 + srow) * K;

  f32x4 acc[4];
  #pragma unroll
  for (int nf = 0; nf < 4; ++nf) acc[nf] = (f32x4){0.f, 0.f, 0.f, 0.f};

  for (int k0 = 0; k0 < K; k0 += 32) {
    float va[8], vw[8];
    if (k0 + skc + 8 <= K) {
      float4 a0 = *(const float4*)(Ap + k0 + skc);
      float4 a1 = *(const float4*)(Ap + k0 + skc + 4);
      float4 w0 = *(const float4*)(Wp + k0 + skc);
      float4 w1 = *(const float4*)(Wp + k0 + skc + 4);
      va[0]=a0.x; va[1]=a0.y; va[2]=a0.z; va[3]=a0.w;
      va[4]=a1.x; va[5]=a1.y; va[6]=a1.z; va[7]=a1.w;
      vw[0]=w0.x; vw[1]=w0.y; vw[2]=w0.z; vw[3]=w0.w;
      vw[4]=w1.x; vw[5]=w1.y; vw[6]=w1.z; vw[7]=w1.w;
    } else {
      #pragma unroll
      for (int i = 0; i < 8; ++i) { va[i] = 0.f; vw[i] = 0.f; }
    }
    u16x8 AH, AL, WH, WL;
    #pragma unroll
    for (int i = 0; i < 8; ++i) {
      unsigned short h, l;
      split_bf16(va[i], h, l); AH[i] = h; AL[i] = l;
      split_bf16(vw[i], h, l); WH[i] = h; WL[i] = l;
    }
    __syncthreads();
    *(u16x8*)(&Ahi[srow * 40 + skc]) = AH;
    *(u16x8*)(&Alo[srow * 40 + skc]) = AL;
    *(u16x8*)(&Whi[srow * 40 + skc]) = WH;
    *(u16x8*)(&Wlo[srow * 40 + skc]) = WL;
    __syncthreads();
    bf16x8 ah = *(bf16x8*)(&Ahi[(wid * 16 + lm) * 40 + lk * 8]);
    bf16x8 al = *(bf16x8*)(&Alo[(wid * 16 + lm) * 40 + lk * 8]);
    #pragma unroll
    for (int nf = 0; nf < 4; ++nf) {
      bf16x8 bh = *(bf16x8*)(&Whi[(nf * 16 + lm) * 40 + lk * 8]);
      bf16x8 bl = *(bf16x8*)(&Wlo[(nf * 16 + lm) * 40 + lk * 8]);
      acc[nf] = __builtin_amdgcn_mfma_f32_16x16x32_bf16(ah, bh, acc[nf], 0, 0, 0);
      acc[nf] = __builtin_amdgcn_mfma_f32_16x16x32_bf16(ah, bl, acc[nf], 0, 0, 0);
      acc[nf] = __builtin_amdgcn_mfma_f32_16x16x32_bf16(al, bh, acc[nf], 0, 0, 0);
    }
  }
  #pragma unroll
  for (int nf = 0; nf < 4; ++nf) {
    const int gn = bn * 64 + nf * 16 + lm;
    float bb = 0.f;
    if (bias1) bb += bias1[gn];
    if (bias2) bb += bias2[gn];
    #pragma unroll
    for (int r4 = 0; r4 < 4; ++r4) {
      const int gm = bm * 64 + wid * 16 + lk * 4 + r4;
      C[(size_t)gm * N + gn] = acc[nf][r4] + bb;
    }
  }
}

// ---------------------------------------------------------------------------
// x[s*32+b][0:816] = concat(z[b,s], cond[b,s], encoded[b*64+s])
// ---------------------------------------------------------------------------
__global__ __launch_bounds__(256) void build_x_kernel(
    const float* __restrict__ z, const float* __restrict__ cond,
    const float* __restrict__ enc, float* __restrict__ x) {
  const int idx = blockIdx.x * 256 + threadIdx.x;
  const int r = idx / NIN, c = idx % NIN;
  const int s = r >> 5, b = r & 31;
  const int bs = b * NS + s;
  float v;
  if (c < 32)      v = z[bs * 32 + c];
  else if (c < 48) v = cond[bs * 16 + (c - 32)];
  else             v = enc[(size_t)bs * NH + (c - 48)];
  x[idx] = v;
}

// ---------------------------------------------------------------------------
// MERGED 2-layer persistent LSTM (r16 base) with ONE change: the global h
// exchange is bf16-only u16 (was packed hi|lo u32).  Halves the per-epoch
// broadcast read volume (196->98 KB/block) AND the h store volume; staging
// becomes pure 16B copies (zero VALU).  The recurrence operand was already
// bf16 (r16, absmax unchanged); only the head's h precision drops (bf16,
// well within the 1.79e-2 threshold).  Barrier, mapping, MFMA: identical.
// ---------------------------------------------------------------------------
__global__ __launch_bounds__(LTHR)
__attribute__((amdgpu_waves_per_eu(2, 2)))
void lstm_merged(
    const float* __restrict__ xg0,   // [64*32][3072] layer-0 gates (biases folded)
    const float* __restrict__ Whh0,  // [3072][768]
    const float* __restrict__ Wih1,  // [3072][768]
    const float* __restrict__ Whh1,  // [3072][768]
    const float* __restrict__ bih1,  // [3072]
    const float* __restrict__ bhh1,  // [3072]
    const unsigned short* __restrict__ hzero, // [32][768] bf16 zeros
    unsigned short* h0,              // [2048][768] bf16, row = t*32+b
    unsigned short* h1,              // [2048][768] bf16
    unsigned* flags) {               // 192 slots at stride 4 u32, zeroed
  extern __shared__ __align__(16) unsigned short smem_us[];
  unsigned short* pA  = smem_us;                 // [32][HP2] bf16(h0)
  unsigned short* pB  = smem_us + 32 * HP2;      // [32][HP2] bf16(h1)
  float*          gsp = (float*)(smem_us + 2 * 32 * HP2);  // [8][16][33]

  const int tid  = threadIdx.x;
  const int lane = tid & 63;
  const int wid  = tid >> 6;          // 0..7
  const bool wL1 = (wid >= 4);        // waves 4-7 compute layer-1 products
  const int kh   = wid & 3;           // K-quarter (k = kh*192 .. +192)
  const int lm   = lane & 15;
  const int lk   = lane >> 4;
  const int lblk = blockIdx.x;

  // resident Whh frags (L0 or L1 depending on wave -- same registers)
  const int grow = (lm >> 2) * NH + lblk * 4 + (lm & 3);  // gate-row (M=16)
  const float* WhhP = wL1 ? Whh1 : Whh0;
  bf16x8 whi[6], wlo[6];
  #pragma unroll
  for (int s6 = 0; s6 < 6; ++s6) {
    const float* wp = WhhP + (size_t)grow * NH + kh * 192 + s6 * 32 + lk * 8;
    float4 a = *(const float4*)wp;
    float4 b = *(const float4*)(wp + 4);
    float vv[8] = {a.x, a.y, a.z, a.w, b.x, b.y, b.z, b.w};
    #pragma unroll
    for (int i = 0; i < 8; ++i) {
      unsigned short h, l;
      split_bf16(vv[i], h, l);
      whi[s6][i] = (short)h;
      wlo[s6][i] = (short)l;
    }
  }

  // pointwise (tid<256): jp = tid>>5 in 0..7; jp<4 -> L0 cell, else L1
  const int jp = tid >> 5;
  const int bp = tid & 31;
  const bool pwL1 = (jp >= 4);
  const int jloc = jp & 3;
  float c_reg = 0.f;
  float bi = 0.f, bf_ = 0.f, bg = 0.f, bo = 0.f;
  if (tid < 256 && pwL1) {
    const int jj = lblk * 4 + jloc;
    bi  = bih1[0 * NH + jj] + bhh1[0 * NH + jj];
    bf_ = bih1[1 * NH + jj] + bhh1[1 * NH + jj];
    bg  = bih1[2 * NH + jj] + bhh1[2 * NH + jj];
    bo  = bih1[3 * NH + jj] + bhh1[3 * NH + jj];
  }
  const int sb  = tid >> 4;          // staging batch 0..31
  const int sch = tid & 15;          // staging chunk

  for (int e = 0; e <= NS; ++e) {
    const unsigned short* h0r = (e == 0) ? hzero : h0 + (size_t)(e - 1) * NB * NH;
    const unsigned short* h1r = (e <= 1) ? hzero : h1 + (size_t)(e - 2) * NB * NH;
    // L0 xg prefetch (hides under staging/MFMA)
    float xgv0 = 0.f, xgv1 = 0.f, xgv2 = 0.f, xgv3 = 0.f;
    if (tid < 256 && !pwL1 && e < NS) {
      const float* xr = xg0 + (size_t)(e * NB + bp) * G4 + (lblk * 4 + jloc);
      xgv0 = xr[0]; xgv1 = xr[NH]; xgv2 = xr[2 * NH]; xgv3 = xr[3 * NH];
    }
    // ---- stage BOTH planes at epoch top: LLC round-trips overlap ----
    stage_hi(h0r, pA, sb, sch);
    stage_hi(h1r, pB, sb, sch);
    __syncthreads();
    f32x4 acc0 = {0.f, 0.f, 0.f, 0.f};
    f32x4 acc1 = {0.f, 0.f, 0.f, 0.f};
    if (!wL1) {
      // L0: gates = Whh0 . h0(e-1)   (2 products: weight hi + weight lo)
      #pragma unroll
      for (int s6 = 0; s6 < 6; ++s6) {
        const int kb = kh * 192 + s6 * 32 + lk * 8;
        bf16x8 b0 = *(bf16x8*)(&pA[lm * HP2 + kb]);
        bf16x8 b1 = *(bf16x8*)(&pA[(16 + lm) * HP2 + kb]);
        acc0 = __builtin_amdgcn_mfma_f32_16x16x32_bf16(whi[s6], b0, acc0, 0, 0, 0);
        acc0 = __builtin_amdgcn_mfma_f32_16x16x32_bf16(wlo[s6], b0, acc0, 0, 0, 0);
        acc1 = __builtin_amdgcn_mfma_f32_16x16x32_bf16(whi[s6], b1, acc1, 0, 0, 0);
        acc1 = __builtin_amdgcn_mfma_f32_16x16x32_bf16(wlo[s6], b1, acc1, 0, 0, 0);
      }
    } else {
      // L1 phase A: acc = Wih1 . h0(e-1)  (u-frags reloaded, L2-hot)
      #pragma unroll
      for (int s6 = 0; s6 < 6; ++s6) {
        const float* up = Wih1 + (size_t)grow * NH + kh * 192 + s6 * 32 + lk * 8;
        float4 ua = *(const float4*)up;
        float4 ub = *(const float4*)(up + 4);
        float uv[8] = {ua.x, ua.y, ua.z, ua.w, ub.x, ub.y, ub.z, ub.w};
        bf16x8 uh, ul;
        #pragma unroll
        for (int i = 0; i < 8; ++i) {
          unsigned short h, l;
          split_bf16(uv[i], h, l);
          uh[i] = (short)h;
          ul[i] = (short)l;
        }
        const int kb = kh * 192 + s6 * 32 + lk * 8;
        bf16x8 b0 = *(bf16x8*)(&pA[lm * HP2 + kb]);
        bf16x8 b1 = *(bf16x8*)(&pA[(16 + lm) * HP2 + kb]);
        acc0 = __builtin_amdgcn_mfma_f32_16x16x32_bf16(uh, b0, acc0, 0, 0, 0);
        acc0 = __builtin_amdgcn_mfma_f32_16x16x32_bf16(ul, b0, acc0, 0, 0, 0);
        acc1 = __builtin_amdgcn_mfma_f32_16x16x32_bf16(uh, b1, acc1, 0, 0, 0);
        acc1 = __builtin_amdgcn_mfma_f32_16x16x32_bf16(ul, b1, acc1, 0, 0, 0);
      }
      // L1 phase B: acc += Whh1 . h1(e-2)  (resident frags, plane B)
      #pragma unroll
      for (int s6 = 0; s6 < 6; ++s6) {
        const int kb = kh * 192 + s6 * 32 + lk * 8;
        bf16x8 b0 = *(bf16x8*)(&pB[lm * HP2 + kb]);
        bf16x8 b1 = *(bf16x8*)(&pB[(16 + lm) * HP2 + kb]);
        acc0 = __builtin_amdgcn_mfma_f32_16x16x32_bf16(whi[s6], b0, acc0, 0, 0, 0);
        acc0 = __builtin_amdgcn_mfma_f32_16x16x32_bf16(wlo[s6], b0, acc0, 0, 0, 0);
        acc1 = __builtin_amdgcn_mfma_f32_16x16x32_bf16(whi[s6], b1, acc1, 0, 0, 0);
        acc1 = __builtin_amdgcn_mfma_f32_16x16x32_bf16(wlo[s6], b1, acc1, 0, 0, 0);
      }
    }
    #pragma unroll
    for (int r4 = 0; r4 < 4; ++r4) {
      gsp[wid * 528 + (lk * 4 + r4) * 33 + lm]      = acc0[r4];
      gsp[wid * 528 + (lk * 4 + r4) * 33 + 16 + lm] = acc1[r4];
    }
    __syncthreads();
    // ---- pointwise for both layers ----
    if (tid < 256) {
      if (!pwL1) {
        if (e < NS) {
          float sum[4];
          #pragma unroll
          for (int g = 0; g < 4; ++g) {
            const int row = g * 4 + jloc;
            sum[g] = gsp[0 * 528 + row * 33 + bp] + gsp[1 * 528 + row * 33 + bp] +
                     gsp[2 * 528 + row * 33 + bp] + gsp[3 * 528 + row * 33 + bp];
          }
          const float si = 1.f / (1.f + expf(-(sum[0] + xgv0)));
          const float sf = 1.f / (1.f + expf(-(sum[1] + xgv1)));
          const float so = 1.f / (1.f + expf(-(sum[3] + xgv3)));
          c_reg = sf * c_reg + si * tanhf(sum[2] + xgv2);
          const float hnew = so * tanhf(c_reg);
          coh_store_u16(&h0[(size_t)(e * NB + bp) * NH + lblk * 4 + jloc],
                        rne_bf16(hnew));
        }
      } else {
        if (e >= 1) {
          const int t = e - 1;
          float sum[4];
          #pragma unroll
          for (int g = 0; g < 4; ++g) {
            const int row = g * 4 + jloc;
            sum[g] = gsp[4 * 528 + row * 33 + bp] + gsp[5 * 528 + row * 33 + bp] +
                     gsp[6 * 528 + row * 33 + bp] + gsp[7 * 528 + row * 33 + bp];
          }
          const float si = 1.f / (1.f + expf(-(sum[0] + bi)));
          const float sf = 1.f / (1.f + expf(-(sum[1] + bf_)));
          const float so = 1.f / (1.f + expf(-(sum[3] + bo)));
          c_reg = sf * c_reg + si * tanhf(sum[2] + bg);
          const float hnew = so * tanhf(c_reg);
          coh_store_u16(&h1[(size_t)(t * NB + bp) * NH + lblk * 4 + jloc],
                        rne_bf16(hnew));
        }
      }
    }
    // ---- flag-array grid barrier (epochs 0..63; epoch 64 ends kernel) ----
    if (e < NS) {
      __syncthreads();                 // all waves' h stores issued
      if (tid == 0) {
        asm volatile("s_waitcnt vmcnt(0)" ::: "memory");
        __hip_atomic_store(&flags[(unsigned)blockIdx.x * 4], (unsigned)(e + 1),
                           __ATOMIC_RELAXED, __HIP_MEMORY_SCOPE_AGENT);
      }
      if (tid < FBLK) {
        while (__hip_atomic_load(&flags[(unsigned)tid * 4], __ATOMIC_RELAXED,
                                 __HIP_MEMORY_SCOPE_AGENT) < (unsigned)(e + 1))
          __builtin_amdgcn_s_sleep(1);
      }
      __syncthreads();
    }
  }
}

// ---------------------------------------------------------------------------
// preds[b*24+s] = dot(bf16(h1[s*32+b]), Wout) + bout
// ---------------------------------------------------------------------------
__global__ __launch_bounds__(64) void head_kernel(
    const unsigned short* __restrict__ h1, const float* __restrict__ Wout,
    const float* __restrict__ bout, float* __restrict__ preds) {
  const int o = blockIdx.x;
  const int b = o / HOR_, s = o % HOR_;
  const int l = threadIdx.x;
  const unsigned short* h = h1 + (size_t)(s * NB + b) * NH;
  float acc = 0.f;
  #pragma unroll
  for (int k = l; k < NH; k += 64) {
    const float v = __uint_as_float(((unsigned)h[k]) << 16);
    acc += v * Wout[k];
  }
  #pragma unroll
  for (int m = 32; m; m >>= 1) acc += __shfl_xor(acc, m);
  if (l == 0) preds[o] = acc + bout[0];
}

// ---------------------------------------------------------------------------
extern "C" void kernel_launch(void* const* d_in, const int* in_sizes, int n_in,
                              void* d_out, int out_size, void* d_ws, size_t ws_size,
                              hipStream_t stream) {
  const float* z    = (const float*)d_in[0];
  const float* cond = (const float*)d_in[1];
  const float* encs = (const float*)d_in[2];
  const float* W1   = (const float*)d_in[4];
  const float* b1   = (const float*)d_in[5];
  const float* W2   = (const float*)d_in[6];
  const float* b2   = (const float*)d_in[7];
  const float* Wih0 = (const float*)d_in[8];
  const float* Whh0 = (const float*)d_in[9];
  const float* bih0 = (const float*)d_in[10];
  const float* bhh0 = (const float*)d_in[11];
  const float* Wih1 = (const float*)d_in[12];
  const float* Whh1 = (const float*)d_in[13];
  const float* bih1 = (const float*)d_in[14];
  const float* bhh1 = (const float*)d_in[15];
  const float* Wout = (const float*)d_in[16];
  const float* bout = (const float*)d_in[17];

  float* out     = (float*)d_out;
  float* preds   = out;
  float* enc_out = out + NB * HOR_;

  float* ws    = (float*)d_ws;
  float* xb    = ws + OFF_X;
  float* mean  = ws + OFF_MEAN;
  float* tmp   = ws + OFF_TMP;
  unsigned short* h0 = (unsigned short*)(ws + OFF_H0PK);
  unsigned short* h1 = (unsigned short*)(ws + OFF_H1PK);
  float* xg    = ws + OFF_XG;
  unsigned short* hzero = (unsigned short*)(ws + OFF_HZERO);
  unsigned* flags = (unsigned*)(ws + OFF_FLG);

  // allow >64KB dynamic LDS for the persistent kernel
  (void)hipFuncSetAttribute(reinterpret_cast<const void*>(lstm_merged),
                            hipFuncAttributeMaxDynamicSharedMemorySize,
                            160 * 1024);

  // 1. segment mean (filter and mean are linear and commute -> pool first)
  seg_mean_kernel<<<NSEG_, 192, 0, stream>>>(encs, mean);
  // 2. encoded = (mean @ W1^T + b1) @ W2^T + b2 -> straight into d_out (MFMA)
  gemm_mfma_nt<<<dim3(NH / 64, NSEG_ / 64), 256, 0, stream>>>(
      mean, W1, b1, nullptr, tmp, NSEG_, NH, NH);
  gemm_mfma_nt<<<dim3(NH / 64, NSEG_ / 64), 256, 0, stream>>>(
      tmp, W2, b2, nullptr, enc_out, NSEG_, NH, NH);
  // 3. x = concat(z, cond, encoded), time-major rows (s*32+b)
  build_x_kernel<<<(NSEG_ * NIN) / 256, 256, 0, stream>>>(z, cond, enc_out, xb);
  // 4. layer-0 input gates (biases folded in), K=816 (guarded chunks)
  gemm_mfma_nt<<<dim3(G4 / 64, NSEG_ / 64), 256, 0, stream>>>(
      xb, Wih0, bih0, bhh0, xg, NSEG_, G4, NIN);
  // 5. merged, pipelined 2-layer recurrence (layer-1 xg GEMM folded in)
  hipMemsetAsync(hzero, 0, (size_t)(SZ_HZERO + 1024) * sizeof(float), stream);
  lstm_merged<<<FBLK, LTHR, SMEM_BYTES, stream>>>(
      xg, Whh0, Wih1, Whh1, bih1, bhh1, hzero, h0, h1, flags);
  // 6. head
  head_kernel<<<NB * HOR_, 64, 0, stream>>>(h1, Wout, bout, preds);
}